// Round 6
// baseline (387.577 us; speedup 1.0000x reference)
//
#include <hip/hip_runtime.h>
#include <hip/hip_bf16.h>
#include <stdint.h>

#define M_DIM 8192
#define N_DIM 4096
#define K_DIM 4096
#define R_DIM 32
#define KPAD  4160   // 4096 quant cols + 32 lora cols + 32 zero pad = 65 * 64
#define NT    65     // K-tiles of 64
#define QMAXF 7.0f

using bf16_t = __hip_bfloat16;
typedef __attribute__((ext_vector_type(4)))  float f32x4;
typedef __attribute__((ext_vector_type(16))) float f32x16;
typedef __attribute__((ext_vector_type(8)))  short bf16x8;

// ---------------------------------------------------------------------------
// async global->LDS 16B stage (LDS dest = wave-uniform base + lane*16)
// ---------------------------------------------------------------------------
__device__ __forceinline__ void stage16(const void* g, void* l) {
#if defined(__has_builtin) && __has_builtin(__builtin_amdgcn_global_load_lds)
  __builtin_amdgcn_global_load_lds(
      (const __attribute__((address_space(1))) unsigned int*)g,
      (__attribute__((address_space(3))) unsigned int*)l, 16, 0, 0);
#else
  *(uint4*)l = *(const uint4*)g;
#endif
}

// ---------------------------------------------------------------------------
// prep kernel: block-range dispatch of three independent jobs.
//   blocks [0, 8192)      : quant_x  -> Ap cols 0..4095, zero pad 4128..4159
//   blocks [8192, 12288)  : quant_w  -> Bp cols 0..4095, lora_up 4096..4127, pad
//   blocks [12288, 12304) : ldT      (lora_down [K][R] -> bf16 ldT [R][K])
// ---------------------------------------------------------------------------
__global__ __launch_bounds__(256) void prep_kernel(
    const float* __restrict__ x, const float* __restrict__ smooth,
    const float* __restrict__ w, const float* __restrict__ lora_up,
    const float* __restrict__ ld,
    bf16_t* __restrict__ Ap, bf16_t* __restrict__ Bp,
    bf16_t* __restrict__ ldT) {
  const int bid = blockIdx.x;
  const int tid = threadIdx.x;

  if (bid < M_DIM) {                       // ---- quant_x ----
    const int row = bid;
    const int k0  = tid * 16;
    const float* xr = x + (size_t)row * K_DIM + k0;
    const float* sr = smooth + k0;

    float v[16];
#pragma unroll
    for (int i = 0; i < 4; ++i) {
      float4 xv = *(const float4*)(xr + i * 4);
      float4 sv = *(const float4*)(sr + i * 4);
      v[i*4+0] = xv.x * sv.x; v[i*4+1] = xv.y * sv.y;
      v[i*4+2] = xv.z * sv.z; v[i*4+3] = xv.w * sv.w;
    }
    float am = 0.f;
#pragma unroll
    for (int i = 0; i < 16; ++i) am = fmaxf(am, fabsf(v[i]));
    am = fmaxf(am, __shfl_xor(am, 1));
    am = fmaxf(am, __shfl_xor(am, 2));
    const float scale = fmaxf(am / QMAXF, 1e-8f);

    alignas(16) bf16_t o[16];
#pragma unroll
    for (int i = 0; i < 16; ++i) {
      float q = rintf(v[i] / scale);       // IEEE div + round-half-even = jnp
      q = fminf(fmaxf(q, -8.f), 7.f);
      o[i] = __float2bfloat16(q * scale);
    }
    bf16_t* dst = Ap + (size_t)row * KPAD + k0;
    ((uint4*)dst)[0] = ((uint4*)o)[0];
    ((uint4*)dst)[1] = ((uint4*)o)[1];
    if (tid < 32) Ap[(size_t)row * KPAD + 4128 + tid] = __float2bfloat16(0.f);

  } else if (bid < M_DIM + N_DIM) {        // ---- quant_w ----
    const int row = bid - M_DIM;
    const int k0  = tid * 16;
    const float* wr = w + (size_t)row * K_DIM + k0;

    float v[16];
#pragma unroll
    for (int i = 0; i < 4; ++i) {
      float4 wv = *(const float4*)(wr + i * 4);
      v[i*4+0] = wv.x; v[i*4+1] = wv.y; v[i*4+2] = wv.z; v[i*4+3] = wv.w;
    }
    float am = 0.f;
#pragma unroll
    for (int i = 0; i < 16; ++i) am = fmaxf(am, fabsf(v[i]));
    am = fmaxf(am, __shfl_xor(am, 1));
    am = fmaxf(am, __shfl_xor(am, 2));
    const float scale = fmaxf(am / QMAXF, 1e-8f);

    alignas(16) bf16_t o[16];
#pragma unroll
    for (int i = 0; i < 16; ++i) {
      float q = rintf(v[i] / scale);
      q = fminf(fmaxf(q, -8.f), 7.f);
      o[i] = __float2bfloat16(q * scale);
    }
    bf16_t* dst = Bp + (size_t)row * KPAD + k0;
    ((uint4*)dst)[0] = ((uint4*)o)[0];
    ((uint4*)dst)[1] = ((uint4*)o)[1];
    if (tid < 32) {
      Bp[(size_t)row * KPAD + 4096 + tid] = __float2bfloat16(lora_up[row * R_DIM + tid]);
    } else if (tid < 64) {
      Bp[(size_t)row * KPAD + 4096 + tid] = __float2bfloat16(0.f);
    }

  } else {                                 // ---- ldT ----
    const int k = (bid - M_DIM - N_DIM) * 256 + tid;
    float v[R_DIM];
#pragma unroll
    for (int i = 0; i < R_DIM / 4; ++i) {
      float4 a = *(const float4*)(ld + (size_t)k * R_DIM + i * 4);
      v[i*4+0] = a.x; v[i*4+1] = a.y; v[i*4+2] = a.z; v[i*4+3] = a.w;
    }
#pragma unroll
    for (int r = 0; r < R_DIM; ++r)
      ldT[(size_t)r * K_DIM + k] = __float2bfloat16(v[r]);
  }
}

// ---------------------------------------------------------------------------
// t = (x*smooth) @ lora_down  [M x 32] via MFMA -> Ap cols 4096..4127.
// ---------------------------------------------------------------------------
__global__ __launch_bounds__(256) void lora_mfma_kernel(
    const float* __restrict__ x, const float* __restrict__ smooth,
    const bf16_t* __restrict__ ldT, bf16_t* __restrict__ Ap) {
  const int tid  = threadIdx.x;
  const int w    = tid >> 6;
  const int lane = tid & 63;
  const int m0   = blockIdx.x * 32;

  const int mrow = m0 + (w >> 1) * 16 + (lane & 15);
  const int ncol = (w & 1) * 16 + (lane & 15);
  const float* xr = x + (size_t)mrow * K_DIM;
  const bf16_t* br = ldT + (size_t)ncol * K_DIM;

  f32x4 acc = {0.f, 0.f, 0.f, 0.f};
  union { bf16_t h[8]; bf16x8 v; } au;

  for (int k = 0; k < K_DIM; k += 32) {
    const int kf = k + (lane >> 4) * 8;
    float4 x0 = *(const float4*)(xr + kf);
    float4 x1 = *(const float4*)(xr + kf + 4);
    float4 s0 = *(const float4*)(smooth + kf);
    float4 s1 = *(const float4*)(smooth + kf + 4);
    au.h[0] = __float2bfloat16(x0.x * s0.x);
    au.h[1] = __float2bfloat16(x0.y * s0.y);
    au.h[2] = __float2bfloat16(x0.z * s0.z);
    au.h[3] = __float2bfloat16(x0.w * s0.w);
    au.h[4] = __float2bfloat16(x1.x * s1.x);
    au.h[5] = __float2bfloat16(x1.y * s1.y);
    au.h[6] = __float2bfloat16(x1.z * s1.z);
    au.h[7] = __float2bfloat16(x1.w * s1.w);
    bf16x8 bv = *(const bf16x8*)(br + kf);
    acc = __builtin_amdgcn_mfma_f32_16x16x32_bf16(au.v, bv, acc, 0, 0, 0);
  }

  const int orow = m0 + (w >> 1) * 16 + (lane >> 4) * 4;
  const int ocol = 4096 + ncol;
#pragma unroll
  for (int q = 0; q < 4; ++q)
    Ap[(size_t)(orow + q) * KPAD + ocol] = __float2bfloat16(acc[q]);
}

// ---------------------------------------------------------------------------
// 256x256x64 2-PHASE GEMM with mfma_f32_32x32x16_bf16.
// 8 waves (2M x 4N); per-wave output 128x64 = 4 row-tiles x 2 col-tiles of
// 32x32 (acc = 8 x f32x16).  LDS: 2 dbuf x (A[256][64] + B[256][64]) bf16 =
// 128 KiB.  A LDS row = rt*64 + wm*32 + r (rt-major so half h = rt{0,1}/{2,3}
// = 16 KiB contiguous, staged exactly as before).  Per ktile:
//   P0: read all B(u) (8 x b128) + A-half0(u) (8); stage A2(u+1)->buf^1;
//       barrier; lgkm(0); 16 MFMA (rt0,rt1); barrier.
//   P1: read A-half1(u) (8); stage B1,B2,A1(u+2)->buf; vmcnt(6)
//       [per-wave queue: 6+2+6=14 -> retire 8 = all of ktile u+1];
//       barrier; lgkm(0); 16 MFMA (rt2,rt3); barrier.
// Swizzle: 16B granule ^= (row&7) both sides (0-conflict, verified r2).
// Operand layouts (32x32x16): A/B row(col)=lane&31, k=(lane>>5)*8+j;
// C/D col=lane&31, row=(e&3)+8*(e>>2)+4*(lane>>5)  [m74/m101].
// ---------------------------------------------------------------------------
__global__ __launch_bounds__(512, 2) void gemm_kernel(
    const bf16_t* __restrict__ A, const bf16_t* __restrict__ B,
    const float* __restrict__ bias, float* __restrict__ C) {
  extern __shared__ __align__(16) bf16_t lds[];   // 65536 elems = 128 KiB

  // XCD-aware swizzle: nwg = 512, divisible by 8
  const int wg  = blockIdx.x;
  const int swz = (wg & 7) * 64 + (wg >> 3);
  const int bn  = swz & 15;    // 0..15
  const int bm  = swz >> 4;    // 0..31

  const int tid  = threadIdx.x;
  const int lane = tid & 63;
  const int wid  = tid >> 6;     // 0..7
  const int wm   = wid >> 2;     // 0..1
  const int wn   = wid & 3;      // 0..3

  const int l31 = lane & 31;     // frag row/col within 32
  const int lh  = lane >> 5;     // k-half selector
  const int l7  = lane & 7;      // swizzle key (row&7 == lane&7 for all reads)

  // staging geometry (identical to rounds 2-5, verified)
  const int sr   = tid >> 3;                 // 0..63
  const int sl   = tid & 7;                  // granule slot
  const int gcol = (sl ^ (sr & 7)) * 8;      // inverse-swizzled source col
  const bf16_t* Abase = A + (size_t)(bm * 256 + ((sr >> 5) & 1) * 128 + (sr & 31)) * KPAD + gcol;
  const bf16_t* Bbase = B + (size_t)(bn * 256 + sr) * KPAD + gcol;
  bf16_t* ldsb = lds;

#define STAGE_A(buf, h, kt) do {                                               \
    stage16(Abase + (size_t)((h) * 2 + 0) * 32 * KPAD + (kt) * 64,             \
            ldsb + (buf) * 32768 + (h) * 8192 + 0 * 4096 + tid * 8);           \
    stage16(Abase + (size_t)((h) * 2 + 1) * 32 * KPAD + (kt) * 64,             \
            ldsb + (buf) * 32768 + (h) * 8192 + 1 * 4096 + tid * 8);           \
  } while (0)
#define STAGE_B(buf, h, kt) do {                                               \
    stage16(Bbase + (size_t)((h) * 128 + 0) * KPAD + (kt) * 64,                \
            ldsb + (buf) * 32768 + 16384 + (h) * 8192 + 0 * 4096 + tid * 8);   \
    stage16(Bbase + (size_t)((h) * 128 + 64) * KPAD + (kt) * 64,               \
            ldsb + (buf) * 32768 + 16384 + (h) * 8192 + 1 * 4096 + tid * 8);   \
  } while (0)

  f32x16 acc[8] = {};   // [rt*2 + ct]
  bf16x8 aF[2][4];      // A frags: [rt within half][kstep]
  bf16x8 bF[2][4];      // B frags: [ct][kstep]

  // swizzled k-granule offsets for ds_read: granule = kt*2 + lh, ^ l7
#define RCOL(kt) ((((kt) * 2 + lh) ^ l7) * 8)

#define LOAD_B_ALL(cb) do {                                                    \
    _Pragma("unroll")                                                          \
    for (int ct = 0; ct < 2; ++ct) {                                           \
      const bf16_t* pb_ = ldsb + (cb) * 32768 + 16384 +                        \
                          (wn * 64 + ct * 32 + l31) * 64;                      \
      _Pragma("unroll")                                                        \
      for (int kt = 0; kt < 4; ++kt) bF[ct][kt] = *(const bf16x8*)(pb_ + RCOL(kt)); \
    }                                                                          \
  } while (0)
#define LOAD_A_HALF(h, cb) do {                                                \
    _Pragma("unroll")                                                          \
    for (int i = 0; i < 2; ++i) {                                              \
      const bf16_t* pa_ = ldsb + (cb) * 32768 +                                \
                          (((h) * 2 + i) * 64 + wm * 32 + l31) * 64;           \
      _Pragma("unroll")                                                        \
      for (int kt = 0; kt < 4; ++kt) aF[i][kt] = *(const bf16x8*)(pa_ + RCOL(kt)); \
    }                                                                          \
  } while (0)
#define MFMA_HALF(h) do {                                                      \
    _Pragma("unroll")                                                          \
    for (int kt = 0; kt < 4; ++kt)                                             \
      _Pragma("unroll")                                                        \
      for (int i = 0; i < 2; ++i)                                              \
        _Pragma("unroll")                                                      \
        for (int ct = 0; ct < 2; ++ct)                                         \
          acc[((h)*2+i)*2+ct] = __builtin_amdgcn_mfma_f32_32x32x16_bf16(       \
              aF[i][kt], bF[ct][kt], acc[((h)*2+i)*2+ct], 0, 0, 0);            \
  } while (0)

#define KTILE2(u, cur) do {                                                    \
    /* ---- P0: B(u) + A-half0(u); stage A2(u+1) ---- */                       \
    LOAD_B_ALL(cur);                                                           \
    LOAD_A_HALF(0, cur);                                                       \
    if ((u) + 1 < NT) STAGE_A((cur) ^ 1, 1, (u) + 1);                          \
    __builtin_amdgcn_s_barrier();                                              \
    asm volatile("s_waitcnt lgkmcnt(0)" ::: "memory");                         \
    __builtin_amdgcn_s_setprio(1);                                             \
    MFMA_HALF(0);                                                              \
    __builtin_amdgcn_s_setprio(0);                                             \
    __builtin_amdgcn_s_barrier();                                              \
    /* ---- P1: A-half1(u); stage B1,B2,A1(u+2); counted wait ---- */          \
    LOAD_A_HALF(1, cur);                                                       \
    if ((u) + 2 < NT) {                                                        \
      STAGE_B(cur, 0, (u) + 2);                                                \
      STAGE_B(cur, 1, (u) + 2);                                                \
      STAGE_A(cur, 0, (u) + 2);                                                \
      asm volatile("s_waitcnt vmcnt(6)" ::: "memory");                         \
    } else {                                                                   \
      asm volatile("s_waitcnt vmcnt(0)" ::: "memory");                         \
    }                                                                          \
    __builtin_amdgcn_s_barrier();                                              \
    asm volatile("s_waitcnt lgkmcnt(0)" ::: "memory");                         \
    __builtin_amdgcn_s_setprio(1);                                             \
    MFMA_HALF(1);                                                              \
    __builtin_amdgcn_s_setprio(0);                                             \
    __builtin_amdgcn_s_barrier();                                              \
  } while (0)

  // ---- prologue: ktile0 fully + ktile1's B1,B2,A1 -> vmcnt(6) commits k0 ----
  STAGE_B(0, 0, 0); STAGE_B(0, 1, 0); STAGE_A(0, 0, 0); STAGE_A(0, 1, 0);
  STAGE_B(1, 0, 1); STAGE_B(1, 1, 1); STAGE_A(1, 0, 1);
  asm volatile("s_waitcnt vmcnt(6)" ::: "memory");
  __builtin_amdgcn_s_barrier();

  for (int base = 0; base < 64; base += 2) {
    KTILE2(base,     0);
    KTILE2(base + 1, 1);
  }
  KTILE2(64, 0);

  // ---- epilogue: 32x32 C/D: col=lane&31, row=(e&3)+8*(e>>2)+4*(lane>>5) ----
#pragma unroll
  for (int rt = 0; rt < 4; ++rt) {
#pragma unroll
    for (int ct = 0; ct < 2; ++ct) {
      const int gc = bn * 256 + wn * 64 + ct * 32 + l31;
      const float bv = bias[gc];
      const int gr0 = bm * 256 + wm * 128 + rt * 32 + lh * 4;
#pragma unroll
      for (int e = 0; e < 16; ++e) {
        const int gr = gr0 + (e & 3) + 8 * (e >> 2);
        C[(size_t)gr * N_DIM + gc] = acc[rt * 2 + ct][e] + bv;
      }
    }
  }
#undef STAGE_A
#undef STAGE_B
#undef RCOL
#undef LOAD_B_ALL
#undef LOAD_A_HALF
#undef MFMA_HALF
#undef KTILE2
}

// ---------------------------------------------------------------------------
extern "C" void kernel_launch(void* const* d_in, const int* in_sizes, int n_in,
                              void* d_out, int out_size, void* d_ws, size_t ws_size,
                              hipStream_t stream) {
  const float* x         = (const float*)d_in[0];
  const float* w_res     = (const float*)d_in[1];
  const float* lora_down = (const float*)d_in[2];
  const float* lora_up   = (const float*)d_in[3];
  const float* smooth    = (const float*)d_in[4];
  const float* b         = (const float*)d_in[5];
  float* out = (float*)d_out;

  // workspace: Ap [M][KPAD] bf16 (68.2 MB), Bp [N][KPAD] bf16 (34.1 MB),
  // ldT [R][K] bf16 (256 KB)
  bf16_t* Ap  = (bf16_t*)d_ws;
  bf16_t* Bp  = Ap + (size_t)M_DIM * KPAD;
  bf16_t* ldT = Bp + (size_t)N_DIM * KPAD;

  // allow 128 KiB dynamic LDS (idempotent, host-side, capture-safe)
  hipFuncSetAttribute((const void*)gemm_kernel,
                      hipFuncAttributeMaxDynamicSharedMemorySize, 131072);

  prep_kernel<<<M_DIM + N_DIM + K_DIM / 256, 256, 0, stream>>>(
      x, smooth, w_res, lora_up, lora_down, Ap, Bp, ldT);
  lora_mfma_kernel<<<M_DIM / 32, 256, 0, stream>>>(x, smooth, ldT, Ap);
  gemm_kernel<<<(M_DIM / 256) * (N_DIM / 256), 512, 131072, stream>>>(Ap, Bp, b, out);
}

// Round 7
// 377.664 us; speedup vs baseline: 1.0262x; 1.0262x over previous
//
#include <hip/hip_runtime.h>
#include <hip/hip_bf16.h>
#include <stdint.h>

#define M_DIM 8192
#define N_DIM 4096
#define K_DIM 4096
#define R_DIM 32
#define KPAD  4160   // 4096 quant cols + 32 lora cols + 32 zero pad = 65 * 64
#define NT    65     // K-tiles of 64
#define QMAXF 7.0f

using bf16_t = __hip_bfloat16;
typedef __attribute__((ext_vector_type(4)))  float f32x4;
typedef __attribute__((ext_vector_type(16))) float f32x16;
typedef __attribute__((ext_vector_type(8)))  short bf16x8;

// ---------------------------------------------------------------------------
// async global->LDS 16B stage (LDS dest = wave-uniform base + lane*16)
// ---------------------------------------------------------------------------
__device__ __forceinline__ void stage16(const void* g, void* l) {
#if defined(__has_builtin) && __has_builtin(__builtin_amdgcn_global_load_lds)
  __builtin_amdgcn_global_load_lds(
      (const __attribute__((address_space(1))) unsigned int*)g,
      (__attribute__((address_space(3))) unsigned int*)l, 16, 0, 0);
#else
  *(uint4*)l = *(const uint4*)g;
#endif
}

// ---------------------------------------------------------------------------
// prep kernel: block-range dispatch of three independent jobs.
//   blocks [0, 8192)      : quant_x  -> Ap cols 0..4095, zero pad 4128..4159
//   blocks [8192, 12288)  : quant_w  -> Bp cols 0..4095, lora_up 4096..4127, pad
//   blocks [12288, 12304) : ldT      (lora_down [K][R] -> bf16 ldT [R][K])
// ---------------------------------------------------------------------------
__global__ __launch_bounds__(256) void prep_kernel(
    const float* __restrict__ x, const float* __restrict__ smooth,
    const float* __restrict__ w, const float* __restrict__ lora_up,
    const float* __restrict__ ld,
    bf16_t* __restrict__ Ap, bf16_t* __restrict__ Bp,
    bf16_t* __restrict__ ldT) {
  const int bid = blockIdx.x;
  const int tid = threadIdx.x;

  if (bid < M_DIM) {                       // ---- quant_x ----
    const int row = bid;
    const int k0  = tid * 16;
    const float* xr = x + (size_t)row * K_DIM + k0;
    const float* sr = smooth + k0;

    float v[16];
#pragma unroll
    for (int i = 0; i < 4; ++i) {
      float4 xv = *(const float4*)(xr + i * 4);
      float4 sv = *(const float4*)(sr + i * 4);
      v[i*4+0] = xv.x * sv.x; v[i*4+1] = xv.y * sv.y;
      v[i*4+2] = xv.z * sv.z; v[i*4+3] = xv.w * sv.w;
    }
    float am = 0.f;
#pragma unroll
    for (int i = 0; i < 16; ++i) am = fmaxf(am, fabsf(v[i]));
    am = fmaxf(am, __shfl_xor(am, 1));
    am = fmaxf(am, __shfl_xor(am, 2));
    const float scale = fmaxf(am / QMAXF, 1e-8f);

    alignas(16) bf16_t o[16];
#pragma unroll
    for (int i = 0; i < 16; ++i) {
      float q = rintf(v[i] / scale);       // IEEE div + round-half-even = jnp
      q = fminf(fmaxf(q, -8.f), 7.f);
      o[i] = __float2bfloat16(q * scale);
    }
    bf16_t* dst = Ap + (size_t)row * KPAD + k0;
    ((uint4*)dst)[0] = ((uint4*)o)[0];
    ((uint4*)dst)[1] = ((uint4*)o)[1];
    if (tid < 32) Ap[(size_t)row * KPAD + 4128 + tid] = __float2bfloat16(0.f);

  } else if (bid < M_DIM + N_DIM) {        // ---- quant_w ----
    const int row = bid - M_DIM;
    const int k0  = tid * 16;
    const float* wr = w + (size_t)row * K_DIM + k0;

    float v[16];
#pragma unroll
    for (int i = 0; i < 4; ++i) {
      float4 wv = *(const float4*)(wr + i * 4);
      v[i*4+0] = wv.x; v[i*4+1] = wv.y; v[i*4+2] = wv.z; v[i*4+3] = wv.w;
    }
    float am = 0.f;
#pragma unroll
    for (int i = 0; i < 16; ++i) am = fmaxf(am, fabsf(v[i]));
    am = fmaxf(am, __shfl_xor(am, 1));
    am = fmaxf(am, __shfl_xor(am, 2));
    const float scale = fmaxf(am / QMAXF, 1e-8f);

    alignas(16) bf16_t o[16];
#pragma unroll
    for (int i = 0; i < 16; ++i) {
      float q = rintf(v[i] / scale);
      q = fminf(fmaxf(q, -8.f), 7.f);
      o[i] = __float2bfloat16(q * scale);
    }
    bf16_t* dst = Bp + (size_t)row * KPAD + k0;
    ((uint4*)dst)[0] = ((uint4*)o)[0];
    ((uint4*)dst)[1] = ((uint4*)o)[1];
    if (tid < 32) {
      Bp[(size_t)row * KPAD + 4096 + tid] = __float2bfloat16(lora_up[row * R_DIM + tid]);
    } else if (tid < 64) {
      Bp[(size_t)row * KPAD + 4096 + tid] = __float2bfloat16(0.f);
    }

  } else {                                 // ---- ldT ----
    const int k = (bid - M_DIM - N_DIM) * 256 + tid;
    float v[R_DIM];
#pragma unroll
    for (int i = 0; i < R_DIM / 4; ++i) {
      float4 a = *(const float4*)(ld + (size_t)k * R_DIM + i * 4);
      v[i*4+0] = a.x; v[i*4+1] = a.y; v[i*4+2] = a.z; v[i*4+3] = a.w;
    }
#pragma unroll
    for (int r = 0; r < R_DIM; ++r)
      ldT[(size_t)r * K_DIM + k] = __float2bfloat16(v[r]);
  }
}

// ---------------------------------------------------------------------------
// t = (x*smooth) @ lora_down  [M x 32] via MFMA -> Ap cols 4096..4127.
// ---------------------------------------------------------------------------
__global__ __launch_bounds__(256) void lora_mfma_kernel(
    const float* __restrict__ x, const float* __restrict__ smooth,
    const bf16_t* __restrict__ ldT, bf16_t* __restrict__ Ap) {
  const int tid  = threadIdx.x;
  const int w    = tid >> 6;
  const int lane = tid & 63;
  const int m0   = blockIdx.x * 32;

  const int mrow = m0 + (w >> 1) * 16 + (lane & 15);
  const int ncol = (w & 1) * 16 + (lane & 15);
  const float* xr = x + (size_t)mrow * K_DIM;
  const bf16_t* br = ldT + (size_t)ncol * K_DIM;

  f32x4 acc = {0.f, 0.f, 0.f, 0.f};
  union { bf16_t h[8]; bf16x8 v; } au;

  for (int k = 0; k < K_DIM; k += 32) {
    const int kf = k + (lane >> 4) * 8;
    float4 x0 = *(const float4*)(xr + kf);
    float4 x1 = *(const float4*)(xr + kf + 4);
    float4 s0 = *(const float4*)(smooth + kf);
    float4 s1 = *(const float4*)(smooth + kf + 4);
    au.h[0] = __float2bfloat16(x0.x * s0.x);
    au.h[1] = __float2bfloat16(x0.y * s0.y);
    au.h[2] = __float2bfloat16(x0.z * s0.z);
    au.h[3] = __float2bfloat16(x0.w * s0.w);
    au.h[4] = __float2bfloat16(x1.x * s1.x);
    au.h[5] = __float2bfloat16(x1.y * s1.y);
    au.h[6] = __float2bfloat16(x1.z * s1.z);
    au.h[7] = __float2bfloat16(x1.w * s1.w);
    bf16x8 bv = *(const bf16x8*)(br + kf);
    acc = __builtin_amdgcn_mfma_f32_16x16x32_bf16(au.v, bv, acc, 0, 0, 0);
  }

  const int orow = m0 + (w >> 1) * 16 + (lane >> 4) * 4;
  const int ocol = 4096 + ncol;
#pragma unroll
  for (int q = 0; q < 4; ++q)
    Ap[(size_t)(orow + q) * KPAD + ocol] = __float2bfloat16(acc[q]);
}

// ---------------------------------------------------------------------------
// 256x256x64 2-PHASE GEMM with mfma_f32_32x32x16_bf16.
// Identical to round 6 EXCEPT the LDS swizzle key: was (row&7), now
// key(row) = (row ^ (row>>3)) & 7.  Rationale: with 32x32 operands the
// read granule only varies with lane bit 5, so lanes {a,a+8,a+16,a+24}
// shared one bank-slot under the old key (2.56e7 conflicts).  The new key
// folds row bits 3-4 in, separating those lanes.  Both sides updated:
//   stage source col = (sl ^ key(sr))*8   [key(LDS row) == key(sr), since
//   every LDS row = sr + multiple of 64; (row>>3)&7 == (sr>>3)&7]
//   read col         = (granule ^ key(read_row))*8
// ---------------------------------------------------------------------------
__global__ __launch_bounds__(512, 2) void gemm_kernel(
    const bf16_t* __restrict__ A, const bf16_t* __restrict__ B,
    const float* __restrict__ bias, float* __restrict__ C) {
  extern __shared__ __align__(16) bf16_t lds[];   // 65536 elems = 128 KiB

  // XCD-aware swizzle: nwg = 512, divisible by 8
  const int wg  = blockIdx.x;
  const int swz = (wg & 7) * 64 + (wg >> 3);
  const int bn  = swz & 15;    // 0..15
  const int bm  = swz >> 4;    // 0..31

  const int tid  = threadIdx.x;
  const int lane = tid & 63;
  const int wid  = tid >> 6;     // 0..7
  const int wm   = wid >> 2;     // 0..1
  const int wn   = wid & 3;      // 0..3

  const int l31 = lane & 31;     // frag row/col within 32
  const int lh  = lane >> 5;     // k-half selector
  const int l7  = lane & 7;
  const int rk  = l31 >> 3;      // row bits 3-4 (0..3)

  // swizzle keys: key(row) = (row ^ (row>>3)) & 7
  // A read row = rt*64 + wm*32 + l31  -> key = l7 ^ ((wm*4 + rk) & 7)
  // B read row = wn*64 + ct*32 + l31  -> key = l7 ^ ((ct*4 + rk) & 7)
  const int keyA  = l7 ^ ((wm * 4 + rk) & 7);
  const int keyB0 = l7 ^ (rk & 7);          // ct=0; ct=1 -> keyB0 ^ 4

  // staging geometry: source col granule = sl ^ key(sr)
  const int sr   = tid >> 3;                 // 0..63
  const int sl   = tid & 7;                  // granule slot
  const int gcol = (sl ^ ((sr ^ (sr >> 3)) & 7)) * 8;
  const bf16_t* Abase = A + (size_t)(bm * 256 + ((sr >> 5) & 1) * 128 + (sr & 31)) * KPAD + gcol;
  const bf16_t* Bbase = B + (size_t)(bn * 256 + sr) * KPAD + gcol;
  bf16_t* ldsb = lds;

#define STAGE_A(buf, h, kt) do {                                               \
    stage16(Abase + (size_t)((h) * 2 + 0) * 32 * KPAD + (kt) * 64,             \
            ldsb + (buf) * 32768 + (h) * 8192 + 0 * 4096 + tid * 8);           \
    stage16(Abase + (size_t)((h) * 2 + 1) * 32 * KPAD + (kt) * 64,             \
            ldsb + (buf) * 32768 + (h) * 8192 + 1 * 4096 + tid * 8);           \
  } while (0)
#define STAGE_B(buf, h, kt) do {                                               \
    stage16(Bbase + (size_t)((h) * 128 + 0) * KPAD + (kt) * 64,                \
            ldsb + (buf) * 32768 + 16384 + (h) * 8192 + 0 * 4096 + tid * 8);   \
    stage16(Bbase + (size_t)((h) * 128 + 64) * KPAD + (kt) * 64,               \
            ldsb + (buf) * 32768 + 16384 + (h) * 8192 + 1 * 4096 + tid * 8);   \
  } while (0)

  f32x16 acc[8] = {};   // [rt*2 + ct]
  bf16x8 aF[2][4];      // A frags: [rt within half][kstep]
  bf16x8 bF[2][4];      // B frags: [ct][kstep]

  // swizzled k-granule offsets for ds_read: granule = kt*2 + lh
#define RCOLA(kt)     ((((kt) * 2 + lh) ^ keyA) * 8)
#define RCOLB(kt, ct) ((((kt) * 2 + lh) ^ keyB0 ^ ((ct) * 4)) * 8)

#define LOAD_B_ALL(cb) do {                                                    \
    _Pragma("unroll")                                                          \
    for (int ct = 0; ct < 2; ++ct) {                                           \
      const bf16_t* pb_ = ldsb + (cb) * 32768 + 16384 +                        \
                          (wn * 64 + ct * 32 + l31) * 64;                      \
      _Pragma("unroll")                                                        \
      for (int kt = 0; kt < 4; ++kt) bF[ct][kt] = *(const bf16x8*)(pb_ + RCOLB(kt, ct)); \
    }                                                                          \
  } while (0)
#define LOAD_A_HALF(h, cb) do {                                                \
    _Pragma("unroll")                                                          \
    for (int i = 0; i < 2; ++i) {                                              \
      const bf16_t* pa_ = ldsb + (cb) * 32768 +                                \
                          (((h) * 2 + i) * 64 + wm * 32 + l31) * 64;           \
      _Pragma("unroll")                                                        \
      for (int kt = 0; kt < 4; ++kt) aF[i][kt] = *(const bf16x8*)(pa_ + RCOLA(kt)); \
    }                                                                          \
  } while (0)
#define MFMA_HALF(h) do {                                                      \
    _Pragma("unroll")                                                          \
    for (int kt = 0; kt < 4; ++kt)                                             \
      _Pragma("unroll")                                                        \
      for (int i = 0; i < 2; ++i)                                              \
        _Pragma("unroll")                                                      \
        for (int ct = 0; ct < 2; ++ct)                                         \
          acc[((h)*2+i)*2+ct] = __builtin_amdgcn_mfma_f32_32x32x16_bf16(       \
              aF[i][kt], bF[ct][kt], acc[((h)*2+i)*2+ct], 0, 0, 0);            \
  } while (0)

#define KTILE2(u, cur) do {                                                    \
    /* ---- P0: B(u) + A-half0(u); stage A2(u+1) ---- */                       \
    LOAD_B_ALL(cur);                                                           \
    LOAD_A_HALF(0, cur);                                                       \
    if ((u) + 1 < NT) STAGE_A((cur) ^ 1, 1, (u) + 1);                          \
    __builtin_amdgcn_s_barrier();                                              \
    asm volatile("s_waitcnt lgkmcnt(0)" ::: "memory");                         \
    __builtin_amdgcn_s_setprio(1);                                             \
    MFMA_HALF(0);                                                              \
    __builtin_amdgcn_s_setprio(0);                                             \
    __builtin_amdgcn_s_barrier();                                              \
    /* ---- P1: A-half1(u); stage B1,B2,A1(u+2); counted wait ---- */          \
    LOAD_A_HALF(1, cur);                                                       \
    if ((u) + 2 < NT) {                                                        \
      STAGE_B(cur, 0, (u) + 2);                                                \
      STAGE_B(cur, 1, (u) + 2);                                                \
      STAGE_A(cur, 0, (u) + 2);                                                \
      asm volatile("s_waitcnt vmcnt(6)" ::: "memory");                         \
    } else {                                                                   \
      asm volatile("s_waitcnt vmcnt(0)" ::: "memory");                         \
    }                                                                          \
    __builtin_amdgcn_s_barrier();                                              \
    asm volatile("s_waitcnt lgkmcnt(0)" ::: "memory");                         \
    __builtin_amdgcn_s_setprio(1);                                             \
    MFMA_HALF(1);                                                              \
    __builtin_amdgcn_s_setprio(0);                                             \
    __builtin_amdgcn_s_barrier();                                              \
  } while (0)

  // ---- prologue: ktile0 fully + ktile1's B1,B2,A1 -> vmcnt(6) commits k0 ----
  STAGE_B(0, 0, 0); STAGE_B(0, 1, 0); STAGE_A(0, 0, 0); STAGE_A(0, 1, 0);
  STAGE_B(1, 0, 1); STAGE_B(1, 1, 1); STAGE_A(1, 0, 1);
  asm volatile("s_waitcnt vmcnt(6)" ::: "memory");
  __builtin_amdgcn_s_barrier();

  for (int base = 0; base < 64; base += 2) {
    KTILE2(base,     0);
    KTILE2(base + 1, 1);
  }
  KTILE2(64, 0);

  // ---- epilogue: 32x32 C/D: col=lane&31, row=(e&3)+8*(e>>2)+4*(lane>>5) ----
#pragma unroll
  for (int rt = 0; rt < 4; ++rt) {
#pragma unroll
    for (int ct = 0; ct < 2; ++ct) {
      const int gc = bn * 256 + wn * 64 + ct * 32 + l31;
      const float bv = bias[gc];
      const int gr0 = bm * 256 + wm * 128 + rt * 32 + lh * 4;
#pragma unroll
      for (int e = 0; e < 16; ++e) {
        const int gr = gr0 + (e & 3) + 8 * (e >> 2);
        C[(size_t)gr * N_DIM + gc] = acc[rt * 2 + ct][e] + bv;
      }
    }
  }
#undef STAGE_A
#undef STAGE_B
#undef RCOLA
#undef RCOLB
#undef LOAD_B_ALL
#undef LOAD_A_HALF
#undef MFMA_HALF
#undef KTILE2
}

// ---------------------------------------------------------------------------
extern "C" void kernel_launch(void* const* d_in, const int* in_sizes, int n_in,
                              void* d_out, int out_size, void* d_ws, size_t ws_size,
                              hipStream_t stream) {
  const float* x         = (const float*)d_in[0];
  const float* w_res     = (const float*)d_in[1];
  const float* lora_down = (const float*)d_in[2];
  const float* lora_up   = (const float*)d_in[3];
  const float* smooth    = (const float*)d_in[4];
  const float* b         = (const float*)d_in[5];
  float* out = (float*)d_out;

  // workspace: Ap [M][KPAD] bf16 (68.2 MB), Bp [N][KPAD] bf16 (34.1 MB),
  // ldT [R][K] bf16 (256 KB)
  bf16_t* Ap  = (bf16_t*)d_ws;
  bf16_t* Bp  = Ap + (size_t)M_DIM * KPAD;
  bf16_t* ldT = Bp + (size_t)N_DIM * KPAD;

  // allow 128 KiB dynamic LDS (idempotent, host-side, capture-safe)
  hipFuncSetAttribute((const void*)gemm_kernel,
                      hipFuncAttributeMaxDynamicSharedMemorySize, 131072);

  prep_kernel<<<M_DIM + N_DIM + K_DIM / 256, 256, 0, stream>>>(
      x, smooth, w_res, lora_up, lora_down, Ap, Bp, ldT);
  lora_mfma_kernel<<<M_DIM / 32, 256, 0, stream>>>(x, smooth, ldT, Ap);
  gemm_kernel<<<(M_DIM / 256) * (N_DIM / 256), 512, 131072, stream>>>(Ap, Bp, b, out);
}